// Round 5
// baseline (98.801 us; speedup 1.0000x reference)
//
#include <hip/hip_runtime.h>
#include <stdint.h>

#define NQ 12
#define DIM 4096
#define NLAYERS 6
#define TPB 256

typedef float v2f __attribute__((ext_vector_type(2)));

// ---------------------------------------------------------------------------
// R17: dual batch element per THREAD (PRA/PRB), R12's 17-pass layout, with
// every LDS drain point covered by the other state's gate VALU.
//   Grid 256 x 256 threads; block b holds batch 2b (A) and 2b+1 (B) in regs.
//   k bits: 0-2 local, 3 pack, 4-9 lane (tid 0-5), 10-11 wave (tid 6-7).
//   Per layer: [rebase cross] win1 [P_a wl] win2 [P_b cross] win3
//   Schedule (steady layer): every write group followed by other state's
//   window before its drain; barriers placed where outstanding DS is already
//   consumed or covered:
//     Rw(A) packB3' Rw(B) BAR Rr(A) Rr(B) winA1
//     paw(A) winB1 [lgkm0 par(A)] paw(B) winA2 [lgkm0 par(B)]
//     pbw(A) winB2 pbw(B) BAR pbr(A) pbr(B) winqA3 winqB3 BAR packA3 -> next
//   (win = 3 gate_q + pack ; winq = 3 gate_q only ; pack deferred to cover
//    the next rebase writes.)
//   Buffers: pa [0,2D) wave-private, A/B time-share (in-order DS retire);
//   XA [2D,4D), XB [4D,6D): per-state rebase+P_b (write->read separated by
//   the phase barrier; reuse across layers separated by the post-winq BAR).
//   LDS 96KB + tables -> 1 block/CU, 4 waves. Hiding is intra-wave ILP.
// ---------------------------------------------------------------------------
struct Pass_t {
    uint32_t WT[8];    // Lambda cols, k bits 4..11
    uint32_t WL[8];    // Lambda(j), local bits 0..2
    uint32_t RT[8];    // (Lambda o M) cols, k bits 4..11
    uint32_t RL[16];   // (Lambda o M)(l), local bits 0..3
};
struct Pass10_t {      // wave-local: 10-bit space (k bits 0..9)
    uint32_t WT[6];
    uint32_t WL[8];
    uint32_t RT[6];
    uint32_t RL[16];
};
struct CK_t {
    Pass10_t PA;           // swap {0-3}<->{4-7}, wave-local
    Pass_t PB;             // swap {0-3}<->{8-11}, cross-wave
    Pass_t P1[NLAYERS];    // rebase (index 1..5 used)
    uint32_t frow[NQ];     // epilogue sign rows
};

constexpr uint32_t G2f(uint32_t k){ return ((k&15u)<<8) | (k&0xF0u) | ((k>>8)&15u); }
constexpr uint32_t G3f(uint32_t k){ return ((k&15u)<<4) | ((k>>4)&15u) | (k&0xF00u); }

constexpr uint32_t ech_reduce(const uint32_t* v, int n, uint32_t x){
    bool ch = true;
    while (ch) {
        ch = false;
        for (int i = 0; i < n; i++)
            if (v[i] && (x ^ v[i]) < x) { x ^= v[i]; ch = true; }
    }
    return x;
}

constexpr Pass_t build_pass(const uint32_t* Mc) {
    Pass_t P{};
    uint32_t rows[12]{};
    rows[0] = 8u;                              // row0 = pack functional
    int nr = 1;
    uint32_t full[12]{}; int nf = 0; full[nf++] = 8u;
    uint32_t We[4]{};  int nw = 0;
    uint32_t Re[5]{};  int nre = 0;
    {   // row0's read projection over span Mc[4..8]
        uint32_t p0 = 0;
        for (int j = 0; j < 5; j++)
            p0 |= (uint32_t)(__builtin_popcount(8u & Mc[4 + j]) & 1) << j;
        uint32_t r = ech_reduce(Re, nre, p0);
        if (r) Re[nre++] = r;
    }
    for (int slot = 0; slot < 4; slot++) {
        uint32_t chosen = 0;
        for (int relax = 0; relax < 3 && !chosen; relax++) {
            for (uint32_t m = 1; m < 4096u && !chosen; m++) {
                if (m & 8u) continue;
                uint32_t wp = (m >> 4) & 15u;
                uint32_t wr = ech_reduce(We, nw, wp);
                if (relax < 2 && !wr) continue;
                uint32_t rp = 0;
                for (int j = 0; j < 5; j++)
                    rp |= (uint32_t)(__builtin_popcount(m & Mc[4 + j]) & 1) << j;
                uint32_t rr = ech_reduce(Re, nre, rp);
                if (relax < 1 && !rr) continue;
                uint32_t fr = ech_reduce(full, nf, m);
                if (!fr) continue;
                chosen = m; full[nf++] = fr;
                if (wr && nw < 4) We[nw++] = wr;
                if (rr && nre < 5) Re[nre++] = rr;
            }
        }
        rows[nr++] = chosen;
    }
    for (int slot = nr; slot < 12; slot++) {
        for (uint32_t m = 1; m < 4096u; m++) {
            if (m & 8u) continue;
            uint32_t fr = ech_reduce(full, nf, m);
            if (fr) { rows[slot] = m; full[nf++] = fr; break; }
        }
    }
    uint32_t col[12]{}, lmc[12]{};
    for (int j = 0; j < 12; j++) {
        uint32_t c = 0;
        for (int i = 0; i < 12; i++) c |= (uint32_t)((rows[i] >> j) & 1u) << i;
        col[j] = c;
    }
    for (int j = 0; j < 12; j++) {
        uint32_t a = 0, mc = Mc[j];
        for (int q = 0; q < 12; q++) if ((mc >> q) & 1u) a ^= col[q];
        lmc[j] = a;
    }
    for (int j = 0; j < 8; j++) { P.WT[j] = col[4 + j]; P.RT[j] = lmc[4 + j]; }
    for (int j = 0; j < 8; j++) {
        uint32_t a = 0;
        for (int q = 0; q < 3; q++) if ((j >> q) & 1) a ^= col[q];
        P.WL[j] = a;
    }
    for (int l = 0; l < 16; l++) {
        uint32_t a = 0;
        for (int q = 0; q < 4; q++) if ((l >> q) & 1) a ^= lmc[q];
        P.RL[l] = a;
    }
    return P;
}

constexpr Pass10_t build_pass10(const uint32_t* Mc) {
    Pass10_t P{};
    uint32_t rows[10]{};
    rows[0] = 8u;
    int nr = 1;
    uint32_t full[10]{}; int nf = 0; full[nf++] = 8u;
    uint32_t We[4]{};  int nw = 0;
    uint32_t Re[5]{};  int nre = 0;
    {
        uint32_t p0 = 0;
        for (int j = 0; j < 5; j++)
            p0 |= (uint32_t)(__builtin_popcount(8u & Mc[4 + j]) & 1) << j;
        uint32_t r = ech_reduce(Re, nre, p0);
        if (r) Re[nre++] = r;
    }
    for (int slot = 0; slot < 4; slot++) {
        uint32_t chosen = 0;
        for (int relax = 0; relax < 3 && !chosen; relax++) {
            for (uint32_t m = 1; m < 1024u && !chosen; m++) {
                if (m & 8u) continue;
                uint32_t wp = (m >> 4) & 15u;
                uint32_t wr = ech_reduce(We, nw, wp);
                if (relax < 2 && !wr) continue;
                uint32_t rp = 0;
                for (int j = 0; j < 5; j++)
                    rp |= (uint32_t)(__builtin_popcount(m & Mc[4 + j]) & 1) << j;
                uint32_t rr = ech_reduce(Re, nre, rp);
                if (relax < 1 && !rr) continue;
                uint32_t fr = ech_reduce(full, nf, m);
                if (!fr) continue;
                chosen = m; full[nf++] = fr;
                if (wr && nw < 4) We[nw++] = wr;
                if (rr && nre < 5) Re[nre++] = rr;
            }
        }
        rows[nr++] = chosen;
    }
    for (int slot = nr; slot < 10; slot++) {
        for (uint32_t m = 1; m < 1024u; m++) {
            if (m & 8u) continue;
            uint32_t fr = ech_reduce(full, nf, m);
            if (fr) { rows[slot] = m; full[nf++] = fr; break; }
        }
    }
    uint32_t col[10]{}, lmc[10]{};
    for (int j = 0; j < 10; j++) {
        uint32_t c = 0;
        for (int i = 0; i < 10; i++) c |= (uint32_t)((rows[i] >> j) & 1u) << i;
        col[j] = c;
    }
    for (int j = 0; j < 10; j++) {
        uint32_t a = 0, mc = Mc[j];
        for (int q = 0; q < 10; q++) if ((mc >> q) & 1u) a ^= col[q];
        lmc[j] = a;
    }
    for (int j = 0; j < 6; j++) { P.WT[j] = col[4 + j]; P.RT[j] = lmc[4 + j]; }
    for (int j = 0; j < 8; j++) {
        uint32_t a = 0;
        for (int q = 0; q < 3; q++) if ((j >> q) & 1) a ^= col[q];
        P.WL[j] = a;
    }
    for (int l = 0; l < 16; l++) {
        uint32_t a = 0;
        for (int q = 0; q < 4; q++) if ((l >> q) & 1) a ^= lmc[q];
        P.RL[l] = a;
    }
    return P;
}

constexpr CK_t build_ck() {
    CK_t ck{};
    uint32_t Acols[NLAYERS][NQ]{}, Aicol5[NQ]{};
    for (int l = 0; l < NLAYERS; l++) {
        int r = l % (NQ - 1) + 1;
        for (int q = 0; q < NQ; q++) {
            uint32_t v = 1u << q;
            for (int w = NQ - 1; w >= 0; w--) {            // A = T0∘T1∘...∘T11
                int pc = NQ - 1 - w, pt = NQ - 1 - ((w + r) % NQ);
                v ^= ((v >> pc) & 1u) << pt;
            }
            Acols[l][q] = v;
            if (l == NLAYERS - 1) {
                uint32_t u = 1u << q;
                for (int w = 0; w < NQ; w++) {             // A^-1
                    int pc = NQ - 1 - w, pt = NQ - 1 - ((w + r) % NQ);
                    u ^= ((u >> pc) & 1u) << pt;
                }
                Aicol5[q] = u;
            }
        }
    }
    uint32_t Mc10[10]{};
    for (int j = 0; j < 10; j++) Mc10[j] = G3f(1u << j);      // M_a
    ck.PA = build_pass10(Mc10);
    uint32_t Mc[12]{};
    for (int j = 0; j < 12; j++) Mc[j] = G2f(1u << j);        // M_b
    ck.PB = build_pass(Mc);
    for (int l = 1; l < NLAYERS; l++) {                       // M_c = M_b.M_a.A
        for (int j = 0; j < 12; j++) Mc[j] = G2f(G3f(Acols[l - 1][j]));
        ck.P1[l] = build_pass(Mc);
    }
    // epilogue: i(k) = A5^-1(Phi(k)), Phi = M_a.M_b  (col: G3f(G2f(e_j)))
    uint32_t Mcol[NQ]{};
    for (int j = 0; j < NQ; j++) {
        uint32_t pj = G3f(G2f(1u << j));
        uint32_t M = 0;
        for (int m = 0; m < NQ; m++) if ((pj >> m) & 1u) M ^= Aicol5[m];
        Mcol[j] = M;
    }
    for (int p = 0; p < NQ; p++) {
        uint32_t s = 0;
        for (int j = 0; j < NQ; j++) s |= ((Mcol[j] >> p) & 1u) << j;
        ck.frow[p] = s;
    }
    return ck;
}
constexpr CK_t CK = build_ck();

// rotation at local bit Q; m = (m00r,m00i,m01r,m01i); element-wise pk math.
template<int Q>
__device__ __forceinline__ void gate_q(v2f (&PRE)[8], v2f (&PIM)[8], float4 m) {
    v2f bx = {m.x, m.x}, by = {m.y, m.y}, bz = {m.z, m.z}, bw = {m.w, m.w};
    #pragma unroll
    for (int j = 0; j < 8; j++) {
        if (j & (1 << Q)) continue;
        int j2 = j | (1 << Q);
        v2f re0 = PRE[j], im0 = PIM[j], re1 = PRE[j2], im1 = PIM[j2];
        PRE[j]  = __builtin_elementwise_fma(bx, re0,
                  __builtin_elementwise_fma(by, -im0,
                  __builtin_elementwise_fma(bz, re1, -bw * im1)));
        PIM[j]  = __builtin_elementwise_fma(bx, im0,
                  __builtin_elementwise_fma(by, re0,
                  __builtin_elementwise_fma(bz, im1, bw * re1)));
        PRE[j2] = __builtin_elementwise_fma(bx, re1,
                  __builtin_elementwise_fma(by, im1,
                  __builtin_elementwise_fma(bz, -re0, -bw * im0)));
        PIM[j2] = __builtin_elementwise_fma(bx, im1,
                  __builtin_elementwise_fma(by, -re1,
                  __builtin_elementwise_fma(bz, -im0, bw * re0)));
    }
}

// gate on the pack bit (halves .x/.y of each v2f), sign-vector pk math.
__device__ __forceinline__ void pack_gate(v2f (&PRE)[8], v2f (&PIM)[8], float4 m) {
    v2f d1 = {-m.y, m.y}, d2 = {m.z, -m.z};
    #pragma unroll
    for (int j = 0; j < 8; j++) {
        v2f RE = PRE[j], IM = PIM[j];
        v2f sR = {RE.y, RE.x}, sI = {IM.y, IM.x};
        PRE[j] = m.x * RE + d1 * IM + d2 * sR - m.w * sI;
        PIM[j] = m.x * IM - d1 * RE + d2 * sI + m.w * sR;
    }
}

// window p -> gates at smat[p+3],[p+2],[p+1] + pack smat[p+0]
__device__ __forceinline__ void winq(v2f (&PRE)[8], v2f (&PIM)[8], const float4* p) {
    gate_q<0>(PRE, PIM, p[3]);
    gate_q<1>(PRE, PIM, p[2]);
    gate_q<2>(PRE, PIM, p[1]);
}
__device__ __forceinline__ void win(v2f (&PRE)[8], v2f (&PIM)[8], const float4* p) {
    winq(PRE, PIM, p);
    pack_gate(PRE, PIM, p[0]);
}

// wave-local P_a halves (pa buf wave-private; A/B time-share via in-order DS)
__device__ __forceinline__ void pa_w(const v2f (&PRE)[8], const v2f (&PIM)[8],
                                     float* buf, uint32_t wb) {
    constexpr Pass10_t P = CK.PA;
    v2f* bre = (v2f*)buf;
    v2f* bim = (v2f*)(buf + DIM);
    #pragma unroll
    for (int j = 0; j < 8; j++) {
        uint32_t s = (wb ^ P.WL[j]) >> 1;
        bre[s] = PRE[j]; bim[s] = PIM[j];
    }
}
__device__ __forceinline__ void pa_r(v2f (&PRE)[8], v2f (&PIM)[8],
                                     const float* buf, uint32_t rb) {
    constexpr Pass10_t P = CK.PA;
    __asm__ volatile("s_waitcnt lgkmcnt(0)" ::: "memory");
    #pragma unroll
    for (int j = 0; j < 8; j++) {
        uint32_t s0 = rb ^ P.RL[j], s1 = rb ^ P.RL[j | 8];
        v2f re, im;
        re.x = buf[s0];       re.y = buf[s1];
        im.x = buf[DIM + s0]; im.y = buf[DIM + s1];
        PRE[j] = re; PIM[j] = im;
    }
}

// cross-wave pass halves (barrier placed by caller between write and read)
__device__ __forceinline__ void cross_w(const v2f (&PRE)[8], const v2f (&PIM)[8],
                                        float* buf, uint32_t wb, const uint32_t* WL) {
    v2f* bre = (v2f*)buf;
    v2f* bim = (v2f*)(buf + DIM);
    #pragma unroll
    for (int j = 0; j < 8; j++) {
        uint32_t s = (wb ^ WL[j]) >> 1;
        bre[s] = PRE[j]; bim[s] = PIM[j];
    }
}
__device__ __forceinline__ void cross_r(v2f (&PRE)[8], v2f (&PIM)[8],
                                        const float* buf, uint32_t rb, const uint32_t* RL) {
    #pragma unroll
    for (int j = 0; j < 8; j++) {
        uint32_t s0 = rb ^ RL[j], s1 = rb ^ RL[j | 8];
        v2f re, im;
        re.x = buf[s0];       re.y = buf[s1];
        im.x = buf[DIM + s0]; im.y = buf[DIM + s1];
        PRE[j] = re; PIM[j] = im;
    }
}

__device__ __forceinline__ void init_state(v2f (&PRE)[8], v2f (&PIM)[8],
                                           const float* scs, const float* sss, int tid) {
    float base = 1.0f;
    #pragma unroll
    for (int j = 0; j < 8; j++) {
        int w = 7 - j;
        base *= ((tid >> j) & 1) ? sss[w] : scs[w];
    }
    float c8 = scs[8], s8 = sss[8];
    #pragma unroll
    for (int j = 0; j < 8; j++) {
        float a = base;
        #pragma unroll
        for (int p = 0; p < 3; p++) {
            int w = NQ - 1 - p;
            a *= ((j >> p) & 1) ? sss[w] : scs[w];
        }
        PRE[j].x = a * c8;  PRE[j].y = a * s8;
        PIM[j].x = 0.0f;    PIM[j].y = 0.0f;
    }
}

__global__ __launch_bounds__(TPB, 1) void qsim_kernel(
    const float* __restrict__ x,        // [512,12]
    const float* __restrict__ weights,  // [6,12,3]
    const float* __restrict__ Wp,       // [12]
    const float* __restrict__ bptr,     // [1]
    float* __restrict__ out)            // [512]
{
    __shared__ float  lds[6 * DIM];     // pa [0,2D) ; XA [2D,4D) ; XB [4D,6D)
    __shared__ float4 smat[NLAYERS * NQ];
    __shared__ float  scsA[NQ], sssA[NQ], scsB[NQ], sssB[NQ];
    __shared__ float  red[8];

    const int tid = threadIdx.x;
    const int b   = blockIdx.x;
    const int bA  = 2 * b, bB = 2 * b + 1;

    if (tid < NQ) {
        float s_, c_;
        sincosf(0.5f * x[bA * NQ + tid], &s_, &c_);
        scsA[tid] = c_; sssA[tid] = s_;
    }
    if (tid >= 64 && tid < 64 + NQ) {
        int q = tid - 64;
        float s_, c_;
        sincosf(0.5f * x[bB * NQ + q], &s_, &c_);
        scsB[q] = c_; sssB[q] = s_;
    }
    if (tid < NLAYERS * NQ) {
        float phi   = weights[tid * 3 + 0];
        float theta = weights[tid * 3 + 1];
        float omega = weights[tid * 3 + 2];
        float st, ct; sincosf(0.5f * theta, &st, &ct);
        float sp, cp; sincosf(0.5f * (phi + omega), &sp, &cp);
        float sm, cm; sincosf(0.5f * (phi - omega), &sm, &cm);
        smat[tid] = make_float4(cp * ct, -sp * ct, -cm * st, -sm * st);
    }
    __syncthreads();

    v2f PRA[8], PIA[8], PRB[8], PIB[8];
    init_state(PRA, PIA, scsA, sssA, tid);
    init_state(PRB, PIB, scsB, sssB, tid);

    // fixed-pass address bases (shared by both states; buffers differ)
    uint32_t pawb = 0, parb = 0, pbwb = 0, pbrb = 0;
    #pragma unroll
    for (int j = 0; j < 6; j++) {
        uint32_t sel = (uint32_t)(-(int)((tid >> j) & 1));
        pawb ^= sel & CK.PA.WT[j]; parb ^= sel & CK.PA.RT[j];
    }
    #pragma unroll
    for (int j = 0; j < 8; j++) {
        uint32_t sel = (uint32_t)(-(int)((tid >> j) & 1));
        pbwb ^= sel & CK.PB.WT[j]; pbrb ^= sel & CK.PB.RT[j];
    }
    {
        uint32_t wvb = (uint32_t)(tid & 0xC0) << 4;   // wave id -> slot bits 10,11
        pawb |= wvb; parb |= wvb;
    }

    float* pabuf = lds;
    float* bufXA = lds + 2 * DIM;
    float* bufXB = lds + 4 * DIM;

    // ---- layer 0 (no rebase) ----
    {
        win(PRA, PIA, &smat[8]);                      // A win1
        pa_w(PRA, PIA, pabuf, pawb);
        win(PRB, PIB, &smat[8]);                      // B win1 (covers A pa writes)
        pa_r(PRA, PIA, pabuf, parb);                  // lgkm0 + reads
        pa_w(PRB, PIB, pabuf, pawb);
        win(PRA, PIA, &smat[4]);                      // A win2 (covers B pa writes)
        pa_r(PRB, PIB, pabuf, parb);
        cross_w(PRA, PIA, bufXA, pbwb, CK.PB.WL);     // A pb writes
        win(PRB, PIB, &smat[4]);                      // B win2 (covers A pb writes)
        cross_w(PRB, PIB, bufXB, pbwb, CK.PB.WL);     // B pb writes (uncovered)
        __syncthreads();
        cross_r(PRA, PIA, bufXA, pbrb, CK.PB.RL);
        cross_r(PRB, PIB, bufXB, pbrb, CK.PB.RL);
        winq(PRA, PIA, &smat[0]);                     // A w3,w2,w1
        winq(PRB, PIB, &smat[0]);                     // B w3,w2,w1
        __syncthreads();                              // cheap: reads consumed
        pack_gate(PRA, PIA, smat[0]);                 // A pack w0
    }

    // ---- layers 1..5 ----
    #pragma clang loop unroll(disable)
    for (int l = 1; l < NLAYERS; l++) {
        const Pass_t& P = CK.P1[l];
        uint32_t rwb = 0, rrb = 0;
        #pragma unroll
        for (int j = 0; j < 8; j++) {
            uint32_t sel = (uint32_t)(-(int)((tid >> j) & 1));
            rwb ^= sel & P.WT[j];
            rrb ^= sel & P.RT[j];
        }
        const int sb = l * NQ, sp = (l - 1) * NQ;

        cross_w(PRA, PIA, bufXA, rwb, P.WL);          // A rebase writes
        pack_gate(PRB, PIB, smat[sp + 0]);            // B pack3(l-1): covers
        cross_w(PRB, PIB, bufXB, rwb, P.WL);          // B rebase writes (uncov.)
        __syncthreads();
        cross_r(PRA, PIA, bufXA, rrb, P.RL);
        cross_r(PRB, PIB, bufXB, rrb, P.RL);
        win(PRA, PIA, &smat[sb + 8]);                 // A win1 (consumes A reads)
        pa_w(PRA, PIA, pabuf, pawb);
        win(PRB, PIB, &smat[sb + 8]);                 // B win1 (covers; consumes B)
        pa_r(PRA, PIA, pabuf, parb);
        pa_w(PRB, PIB, pabuf, pawb);
        win(PRA, PIA, &smat[sb + 4]);                 // A win2 (covers B pa writes)
        pa_r(PRB, PIB, pabuf, parb);
        cross_w(PRA, PIA, bufXA, pbwb, CK.PB.WL);     // A pb writes
        win(PRB, PIB, &smat[sb + 4]);                 // B win2 (covers A pb writes)
        cross_w(PRB, PIB, bufXB, pbwb, CK.PB.WL);     // B pb writes (uncovered)
        __syncthreads();
        cross_r(PRA, PIA, bufXA, pbrb, CK.PB.RL);
        cross_r(PRB, PIB, bufXB, pbrb, CK.PB.RL);
        winq(PRA, PIA, &smat[sb + 0]);                // A w3,w2,w1
        winq(PRB, PIB, &smat[sb + 0]);                // B w3,w2,w1
        __syncthreads();                              // cheap; separates pb reads
        pack_gate(PRA, PIA, smat[sb + 0]);            // A pack w0
    }
    pack_gate(PRB, PIB, smat[(NLAYERS - 1) * NQ + 0]); // B pack w0 (layer 5)

    // expectation: coef = b + sum_p W[11-p]*(1-2*bit_p(i(k))), packed halves
    const float bv = bptr[0];
    float wbT[NQ];
    #pragma unroll
    for (int p = 0; p < NQ; p++) {
        uint32_t row = CK.frow[p];
        int tp = __popc(tid & (int)(row >> 4)) & 1;
        float Wv = Wp[NQ - 1 - p];
        wbT[p] = tp ? -Wv : Wv;
    }
    v2f accA2 = {0.0f, 0.0f}, accB2 = {0.0f, 0.0f};
    #pragma unroll
    for (int j = 0; j < 8; j++) {
        float cx = bv, cy = bv;
        #pragma unroll
        for (int p = 0; p < NQ; p++) {
            uint32_t row = CK.frow[p];
            float s = (__popc(j & (int)(row & 7u)) & 1) ? -wbT[p] : wbT[p];
            cx += s;
            cy += (row & 8u) ? -s : s;
        }
        v2f c = {cx, cy};
        accA2 += (PRA[j] * PRA[j] + PIA[j] * PIA[j]) * c;
        accB2 += (PRB[j] * PRB[j] + PIB[j] * PIB[j]) * c;
    }
    float accA = accA2.x + accA2.y;
    float accB = accB2.x + accB2.y;
    #pragma unroll
    for (int off = 32; off > 0; off >>= 1) {
        accA += __shfl_down(accA, off, 64);
        accB += __shfl_down(accB, off, 64);
    }
    if ((tid & 63) == 0) {
        red[tid >> 6]       = accA;
        red[(tid >> 6) + 4] = accB;
    }
    __syncthreads();
    if (tid == 0) out[bA] = red[0] + red[1] + red[2] + red[3];
    if (tid == 1) out[bB] = red[4] + red[5] + red[6] + red[7];
}

extern "C" void kernel_launch(void* const* d_in, const int* in_sizes, int n_in,
                              void* d_out, int out_size, void* d_ws, size_t ws_size,
                              hipStream_t stream) {
    const float* x       = (const float*)d_in[0];
    const float* weights = (const float*)d_in[1];
    const float* W       = (const float*)d_in[2];
    const float* bptr    = (const float*)d_in[3];
    qsim_kernel<<<256, TPB, 0, stream>>>(x, weights, W, bptr, (float*)d_out);
}

// Round 7
// 94.288 us; speedup vs baseline: 1.0479x; 1.0479x over previous
//
#include <hip/hip_runtime.h>
#include <stdint.h>

#define NQ 12
#define DIM 4096
#define NLAYERS 6
#define TPB 256

typedef float v2f __attribute__((ext_vector_type(2)));

// ---------------------------------------------------------------------------
// R19: R18 with the pairing write-invariant fix.
//   R18 bug: forced read-row y (= row3 of M^-T) could carry bit3; any row
//   (other than row0) with bit3 set breaks col[3]==e0, which the b64
//   pack-pair WRITE hard-assumes (partner at slot s^1). Rebase layers with
//   bit3(y)=1 scrambled the pack partner => absmax 0.07.
//   Fix: pair only when bit3(y)==0 (gate below). P_a (y=e7) and P_b (y=e11)
//   verified bit3-clear => 12/17 passes always paired; rebase layers pair
//   opportunistically, else verbatim-R12 scatter fallback (correct for any
//   full-rank Lambda).
//   Paired pass: lmc[3]=e1 by construction (rows[1]=y, all other rows ⊥ u,
//   row0 ⊥ u via bit3(u)=0 gate) => read pair = (s0, s0+2), bit1(s0)=0
//   guaranteed (solve_y zeroes bit1 of every lmc[q], q!=3) => compiler can
//   merge into ds_read2_b32. Addresses bit-identical to scatter path.
//   Structure otherwise R12 verbatim (17 passes, 256 thr, 2 waves/SIMD).
// ---------------------------------------------------------------------------
struct Pass_t {
    uint32_t WT[8];    // Lambda cols, k bits 4..11
    uint32_t WL[8];    // Lambda(j), local bits 0..2
    uint32_t RT[8];    // (Lambda o M) cols, k bits 4..11
    uint32_t RL[16];   // (Lambda o M)(l), local bits 0..3
    uint32_t paired;   // 1: reads are (s0, s0+2) pairs (lmc[3]==2, bit1(s0)=0)
};
struct Pass10_t {      // wave-local: 10-bit space (k bits 0..9)
    uint32_t WT[6];
    uint32_t WL[8];
    uint32_t RT[6];
    uint32_t RL[16];
    uint32_t paired;
};
struct CK_t {
    Pass10_t PA;           // swap {0-3}<->{4-7}, wave-local
    Pass_t PB;             // swap {0-3}<->{8-11}, cross-wave
    Pass_t P1[NLAYERS];    // rebase (index 1..5 used)
    uint32_t frow[NQ];     // epilogue sign rows
};

constexpr uint32_t G2f(uint32_t k){ return ((k&15u)<<8) | (k&0xF0u) | ((k>>8)&15u); }
constexpr uint32_t G3f(uint32_t k){ return ((k&15u)<<4) | ((k>>4)&15u) | (k&0xF00u); }

constexpr uint32_t ech_reduce(const uint32_t* v, int n, uint32_t x){
    bool ch = true;
    while (ch) {
        ch = false;
        for (int i = 0; i < n; i++)
            if (v[i] && (x ^ v[i]) < x) { x ^= v[i]; ch = true; }
    }
    return x;
}

// solve y (n-bit) with parity(y & Mc[q]) == (q==3), q in [0,n). M invertible
// => unique solution = row 3 of M^-1 (as a row functional).
constexpr uint32_t solve_y(const uint32_t* Mc, int n) {
    uint32_t eq[12]{};
    for (int q = 0; q < n; q++)
        eq[q] = Mc[q] | ((q == 3 ? 1u : 0u) << n);
    int r = 0;
    for (int c = 0; c < n && r < n; c++) {
        int p = -1;
        for (int i = r; i < n; i++) if ((eq[i] >> c) & 1u) { p = i; break; }
        if (p < 0) continue;
        uint32_t t = eq[p]; eq[p] = eq[r]; eq[r] = t;
        for (int i = 0; i < n; i++)
            if (i != r && ((eq[i] >> c) & 1u)) eq[i] ^= eq[r];
        r++;
    }
    uint32_t y = 0;
    for (int i = 0; i < n; i++) {
        uint32_t row = eq[i] & ((1u << n) - 1u);
        if (row && ((eq[i] >> n) & 1u)) {
            int c = 0; while (!((row >> c) & 1u)) c++;
            y |= 1u << c;
        }
    }
    return y;
}

constexpr Pass_t build_pass(const uint32_t* Mc) {
    Pass_t P{};
    const uint32_t u = Mc[3];
    uint32_t paired = ((u >> 3) & 1u) ? 0u : 1u;
    uint32_t y = paired ? solve_y(Mc, 12) : 0u;
    if (y == 0u || (y & 8u)) paired = 0u;      // FIX: bit3(y) must be clear
    uint32_t rows[12]{};
    rows[0] = 8u;                              // row0 = pack functional
    int nr = 1;
    uint32_t full[12]{}; int nf = 0; full[nf++] = 8u;
    uint32_t We[5]{};  int nw = 0;
    uint32_t Re[6]{};  int nre = 0;
    {   // row0's read projection over span Mc[4..8]
        uint32_t p0 = 0;
        for (int j = 0; j < 5; j++)
            p0 |= (uint32_t)(__builtin_popcount(8u & Mc[4 + j]) & 1) << j;
        uint32_t r = ech_reduce(Re, nre, p0);
        if (r) Re[nre++] = r;
    }
    if (paired) {                              // rows[1] = y (forced read row)
        rows[nr++] = y;
        uint32_t fr = ech_reduce(full, nf, y);
        full[nf++] = fr;                       // y has bit3=0, indep of row0
        uint32_t wp = (y >> 4) & 15u;
        uint32_t wr = ech_reduce(We, nw, wp);
        if (wr && nw < 4) We[nw++] = wr;
        uint32_t rp = 0;
        for (int j = 0; j < 5; j++)
            rp |= (uint32_t)(__builtin_popcount(y & Mc[4 + j]) & 1) << j;
        uint32_t rr = ech_reduce(Re, nre, rp);
        if (rr && nre < 5) Re[nre++] = rr;
    }
    const int ngreedy = 5 - nr;                // fill rows up to index 4
    for (int slot = 0; slot < ngreedy; slot++) {
        uint32_t chosen = 0;
        for (int relax = 0; relax < 3 && !chosen; relax++) {
            for (uint32_t m = 1; m < 4096u && !chosen; m++) {
                if (m & 8u) continue;
                if (paired && (__builtin_popcount(m & u) & 1)) continue;
                uint32_t wp = (m >> 4) & 15u;
                uint32_t wr = ech_reduce(We, nw, wp);
                if (relax < 2 && !wr) continue;
                uint32_t rp = 0;
                for (int j = 0; j < 5; j++)
                    rp |= (uint32_t)(__builtin_popcount(m & Mc[4 + j]) & 1) << j;
                uint32_t rr = ech_reduce(Re, nre, rp);
                if (relax < 1 && !rr) continue;
                uint32_t fr = ech_reduce(full, nf, m);
                if (!fr) continue;
                chosen = m; full[nf++] = fr;
                if (wr && nw < 4) We[nw++] = wr;
                if (rr && nre < 5) Re[nre++] = rr;
            }
        }
        rows[nr++] = chosen;
    }
    for (int slot = nr; slot < 12; slot++) {
        for (uint32_t m = 1; m < 4096u; m++) {
            if (m & 8u) continue;
            if (paired && (__builtin_popcount(m & u) & 1)) continue;
            uint32_t fr = ech_reduce(full, nf, m);
            if (fr) { rows[slot] = m; full[nf++] = fr; break; }
        }
    }
    uint32_t col[12]{}, lmc[12]{};
    for (int j = 0; j < 12; j++) {
        uint32_t c = 0;
        for (int i = 0; i < 12; i++) c |= (uint32_t)((rows[i] >> j) & 1u) << i;
        col[j] = c;
    }
    for (int j = 0; j < 12; j++) {
        uint32_t a = 0, mc = Mc[j];
        for (int q = 0; q < 12; q++) if ((mc >> q) & 1u) a ^= col[q];
        lmc[j] = a;
    }
    if (paired && lmc[3] != 2u) paired = 0;    // safety: fallback to scatter
    for (int j = 0; j < 8; j++) { P.WT[j] = col[4 + j]; P.RT[j] = lmc[4 + j]; }
    for (int j = 0; j < 8; j++) {
        uint32_t a = 0;
        for (int q = 0; q < 3; q++) if ((j >> q) & 1) a ^= col[q];
        P.WL[j] = a;
    }
    for (int l = 0; l < 16; l++) {
        uint32_t a = 0;
        for (int q = 0; q < 4; q++) if ((l >> q) & 1) a ^= lmc[q];
        P.RL[l] = a;
    }
    P.paired = paired;
    return P;
}

constexpr Pass10_t build_pass10(const uint32_t* Mc) {
    Pass10_t P{};
    const uint32_t u = Mc[3];
    uint32_t paired = ((u >> 3) & 1u) ? 0u : 1u;
    uint32_t y = paired ? solve_y(Mc, 10) : 0u;
    if (y == 0u || (y & 8u)) paired = 0u;      // FIX: bit3(y) must be clear
    uint32_t rows[10]{};
    rows[0] = 8u;
    int nr = 1;
    uint32_t full[10]{}; int nf = 0; full[nf++] = 8u;
    uint32_t We[5]{};  int nw = 0;
    uint32_t Re[6]{};  int nre = 0;
    {
        uint32_t p0 = 0;
        for (int j = 0; j < 5; j++)
            p0 |= (uint32_t)(__builtin_popcount(8u & Mc[4 + j]) & 1) << j;
        uint32_t r = ech_reduce(Re, nre, p0);
        if (r) Re[nre++] = r;
    }
    if (paired) {
        rows[nr++] = y;
        uint32_t fr = ech_reduce(full, nf, y);
        full[nf++] = fr;
        uint32_t wp = (y >> 4) & 15u;
        uint32_t wr = ech_reduce(We, nw, wp);
        if (wr && nw < 4) We[nw++] = wr;
        uint32_t rp = 0;
        for (int j = 0; j < 5; j++)
            rp |= (uint32_t)(__builtin_popcount(y & Mc[4 + j]) & 1) << j;
        uint32_t rr = ech_reduce(Re, nre, rp);
        if (rr && nre < 5) Re[nre++] = rr;
    }
    const int ngreedy = 5 - nr;
    for (int slot = 0; slot < ngreedy; slot++) {
        uint32_t chosen = 0;
        for (int relax = 0; relax < 3 && !chosen; relax++) {
            for (uint32_t m = 1; m < 1024u && !chosen; m++) {
                if (m & 8u) continue;
                if (paired && (__builtin_popcount(m & u) & 1)) continue;
                uint32_t wp = (m >> 4) & 15u;
                uint32_t wr = ech_reduce(We, nw, wp);
                if (relax < 2 && !wr) continue;
                uint32_t rp = 0;
                for (int j = 0; j < 5; j++)
                    rp |= (uint32_t)(__builtin_popcount(m & Mc[4 + j]) & 1) << j;
                uint32_t rr = ech_reduce(Re, nre, rp);
                if (relax < 1 && !rr) continue;
                uint32_t fr = ech_reduce(full, nf, m);
                if (!fr) continue;
                chosen = m; full[nf++] = fr;
                if (wr && nw < 4) We[nw++] = wr;
                if (rr && nre < 5) Re[nre++] = rr;
            }
        }
        rows[nr++] = chosen;
    }
    for (int slot = nr; slot < 10; slot++) {
        for (uint32_t m = 1; m < 1024u; m++) {
            if (m & 8u) continue;
            if (paired && (__builtin_popcount(m & u) & 1)) continue;
            uint32_t fr = ech_reduce(full, nf, m);
            if (fr) { rows[slot] = m; full[nf++] = fr; break; }
        }
    }
    uint32_t col[10]{}, lmc[10]{};
    for (int j = 0; j < 10; j++) {
        uint32_t c = 0;
        for (int i = 0; i < 10; i++) c |= (uint32_t)((rows[i] >> j) & 1u) << i;
        col[j] = c;
    }
    for (int j = 0; j < 10; j++) {
        uint32_t a = 0, mc = Mc[j];
        for (int q = 0; q < 10; q++) if ((mc >> q) & 1u) a ^= col[q];
        lmc[j] = a;
    }
    if (paired && lmc[3] != 2u) paired = 0;
    for (int j = 0; j < 6; j++) { P.WT[j] = col[4 + j]; P.RT[j] = lmc[4 + j]; }
    for (int j = 0; j < 8; j++) {
        uint32_t a = 0;
        for (int q = 0; q < 3; q++) if ((j >> q) & 1) a ^= col[q];
        P.WL[j] = a;
    }
    for (int l = 0; l < 16; l++) {
        uint32_t a = 0;
        for (int q = 0; q < 4; q++) if ((l >> q) & 1) a ^= lmc[q];
        P.RL[l] = a;
    }
    P.paired = paired;
    return P;
}

constexpr CK_t build_ck() {
    CK_t ck{};
    uint32_t Acols[NLAYERS][NQ]{}, Aicol5[NQ]{};
    for (int l = 0; l < NLAYERS; l++) {
        int r = l % (NQ - 1) + 1;
        for (int q = 0; q < NQ; q++) {
            uint32_t v = 1u << q;
            for (int w = NQ - 1; w >= 0; w--) {            // A = T0∘T1∘...∘T11
                int pc = NQ - 1 - w, pt = NQ - 1 - ((w + r) % NQ);
                v ^= ((v >> pc) & 1u) << pt;
            }
            Acols[l][q] = v;
            if (l == NLAYERS - 1) {
                uint32_t u = 1u << q;
                for (int w = 0; w < NQ; w++) {             // A^-1
                    int pc = NQ - 1 - w, pt = NQ - 1 - ((w + r) % NQ);
                    u ^= ((u >> pc) & 1u) << pt;
                }
                Aicol5[q] = u;
            }
        }
    }
    uint32_t Mc10[10]{};
    for (int j = 0; j < 10; j++) Mc10[j] = G3f(1u << j);      // M_a
    ck.PA = build_pass10(Mc10);
    uint32_t Mc[12]{};
    for (int j = 0; j < 12; j++) Mc[j] = G2f(1u << j);        // M_b
    ck.PB = build_pass(Mc);
    for (int l = 1; l < NLAYERS; l++) {                       // M_c = M_b.M_a.A
        for (int j = 0; j < 12; j++) Mc[j] = G2f(G3f(Acols[l - 1][j]));
        ck.P1[l] = build_pass(Mc);
    }
    // epilogue: i(k) = A5^-1(Phi(k)), Phi = M_a.M_b  (col: G3f(G2f(e_j)))
    uint32_t Mcol[NQ]{};
    for (int j = 0; j < NQ; j++) {
        uint32_t pj = G3f(G2f(1u << j));
        uint32_t M = 0;
        for (int m = 0; m < NQ; m++) if ((pj >> m) & 1u) M ^= Aicol5[m];
        Mcol[j] = M;
    }
    for (int p = 0; p < NQ; p++) {
        uint32_t s = 0;
        for (int j = 0; j < NQ; j++) s |= ((Mcol[j] >> p) & 1u) << j;
        ck.frow[p] = s;
    }
    return ck;
}
constexpr CK_t CK = build_ck();

// rotation at local bit Q; m = (m00r,m00i,m01r,m01i); element-wise pk math.
template<int Q>
__device__ __forceinline__ void gate_q(v2f (&PRE)[8], v2f (&PIM)[8], float4 m) {
    v2f bx = {m.x, m.x}, by = {m.y, m.y}, bz = {m.z, m.z}, bw = {m.w, m.w};
    #pragma unroll
    for (int j = 0; j < 8; j++) {
        if (j & (1 << Q)) continue;
        int j2 = j | (1 << Q);
        v2f re0 = PRE[j], im0 = PIM[j], re1 = PRE[j2], im1 = PIM[j2];
        PRE[j]  = __builtin_elementwise_fma(bx, re0,
                  __builtin_elementwise_fma(by, -im0,
                  __builtin_elementwise_fma(bz, re1, -bw * im1)));
        PIM[j]  = __builtin_elementwise_fma(bx, im0,
                  __builtin_elementwise_fma(by, re0,
                  __builtin_elementwise_fma(bz, im1, bw * re1)));
        PRE[j2] = __builtin_elementwise_fma(bx, re1,
                  __builtin_elementwise_fma(by, im1,
                  __builtin_elementwise_fma(bz, -re0, -bw * im0)));
        PIM[j2] = __builtin_elementwise_fma(bx, im1,
                  __builtin_elementwise_fma(by, -re1,
                  __builtin_elementwise_fma(bz, -im0, bw * re0)));
    }
}

// gate on the pack bit (halves .x/.y of each v2f), sign-vector pk math.
__device__ __forceinline__ void pack_gate(v2f (&PRE)[8], v2f (&PIM)[8], float4 m) {
    v2f d1 = {-m.y, m.y}, d2 = {m.z, -m.z};
    #pragma unroll
    for (int j = 0; j < 8; j++) {
        v2f RE = PRE[j], IM = PIM[j];
        v2f sR = {RE.y, RE.x}, sI = {IM.y, IM.x};
        PRE[j] = m.x * RE + d1 * IM + d2 * sR - m.w * sI;
        PIM[j] = m.x * IM - d1 * RE + d2 * sI + m.w * sR;
    }
}

// wave-local P_a: b64 writes, lgkmcnt drain, paired reads (ds_read2_b32)
__device__ __forceinline__ void pa_pass(v2f (&PRE)[8], v2f (&PIM)[8],
                                        float* buf, uint32_t wb, uint32_t rb) {
    constexpr Pass10_t P = CK.PA;
    v2f* bre = (v2f*)buf;
    v2f* bim = (v2f*)(buf + DIM);
    #pragma unroll
    for (int j = 0; j < 8; j++) {
        uint32_t s = (wb ^ P.WL[j]) >> 1;
        bre[s] = PRE[j]; bim[s] = PIM[j];
    }
    __asm__ volatile("s_waitcnt lgkmcnt(0)" ::: "memory");
    if (P.paired) {
        #pragma unroll
        for (int j = 0; j < 8; j++) {
            uint32_t s0 = rb ^ P.RL[j];          // bit1(s0)==0; partner at +2
            v2f re, im;
            re.x = buf[s0];       re.y = buf[s0 + 2];
            im.x = buf[DIM + s0]; im.y = buf[DIM + s0 + 2];
            PRE[j] = re; PIM[j] = im;
        }
    } else {
        #pragma unroll
        for (int j = 0; j < 8; j++) {
            uint32_t s0 = rb ^ P.RL[j], s1 = rb ^ P.RL[j | 8];
            v2f re, im;
            re.x = buf[s0];       re.y = buf[s1];
            im.x = buf[DIM + s0]; im.y = buf[DIM + s1];
            PRE[j] = re; PIM[j] = im;
        }
    }
}

// cross-wave P_b: pre-barrier (drain P_a reads block-wide), write, barrier, read
__device__ __forceinline__ void pb_pass(v2f (&PRE)[8], v2f (&PIM)[8],
                                        float* buf, uint32_t wb, uint32_t rb) {
    constexpr Pass_t P = CK.PB;
    v2f* bre = (v2f*)buf;
    v2f* bim = (v2f*)(buf + DIM);
    __syncthreads();
    #pragma unroll
    for (int j = 0; j < 8; j++) {
        uint32_t s = (wb ^ P.WL[j]) >> 1;
        bre[s] = PRE[j]; bim[s] = PIM[j];
    }
    __syncthreads();
    if (P.paired) {
        #pragma unroll
        for (int j = 0; j < 8; j++) {
            uint32_t s0 = rb ^ P.RL[j];
            v2f re, im;
            re.x = buf[s0];       re.y = buf[s0 + 2];
            im.x = buf[DIM + s0]; im.y = buf[DIM + s0 + 2];
            PRE[j] = re; PIM[j] = im;
        }
    } else {
        #pragma unroll
        for (int j = 0; j < 8; j++) {
            uint32_t s0 = rb ^ P.RL[j], s1 = rb ^ P.RL[j | 8];
            v2f re, im;
            re.x = buf[s0];       re.y = buf[s1];
            im.x = buf[DIM + s0]; im.y = buf[DIM + s1];
            PRE[j] = re; PIM[j] = im;
        }
    }
}

// cross-wave rebase P_c, runtime layer index (paired flag branched per pass)
__device__ __forceinline__ void rebase_pass(v2f (&PRE)[8], v2f (&PIM)[8],
                                            float* buf, int tid, int l) {
    const Pass_t& P = CK.P1[l];
    uint32_t wb = 0, rb = 0;
    #pragma unroll
    for (int j = 0; j < 8; j++) {
        uint32_t sel = (uint32_t)(-(int)((tid >> j) & 1));
        wb ^= sel & P.WT[j];
        rb ^= sel & P.RT[j];
    }
    v2f* bre = (v2f*)buf;
    v2f* bim = (v2f*)(buf + DIM);
    #pragma unroll
    for (int j = 0; j < 8; j++) {
        uint32_t s = (wb ^ P.WL[j]) >> 1;
        bre[s] = PRE[j]; bim[s] = PIM[j];
    }
    __syncthreads();
    if (P.paired) {
        #pragma unroll
        for (int j = 0; j < 8; j++) {
            uint32_t s0 = rb ^ P.RL[j];
            v2f re, im;
            re.x = buf[s0];       re.y = buf[s0 + 2];
            im.x = buf[DIM + s0]; im.y = buf[DIM + s0 + 2];
            PRE[j] = re; PIM[j] = im;
        }
    } else {
        #pragma unroll
        for (int j = 0; j < 8; j++) {
            uint32_t s0 = rb ^ P.RL[j], s1 = rb ^ P.RL[j | 8];
            v2f re, im;
            re.x = buf[s0];       re.y = buf[s1];
            im.x = buf[DIM + s0]; im.y = buf[DIM + s1];
            PRE[j] = re; PIM[j] = im;
        }
    }
}

__global__ __launch_bounds__(TPB) void qsim_kernel(
    const float* __restrict__ x,        // [512,12]
    const float* __restrict__ weights,  // [6,12,3]
    const float* __restrict__ Wp,       // [12]
    const float* __restrict__ bptr,     // [1]
    float* __restrict__ out)            // [512]
{
    __shared__ float  lds[2 * 2 * DIM]; // bufA [0,8192): P_a/P_b; bufB: rebase
    __shared__ float4 smat[NLAYERS * NQ];
    __shared__ float  scs[NQ], sss[NQ];
    __shared__ float  red[4];

    const int tid = threadIdx.x;
    const int b   = blockIdx.x;

    if (tid < NQ) {
        float s_, c_;
        sincosf(0.5f * x[b * NQ + tid], &s_, &c_);
        scs[tid] = c_; sss[tid] = s_;
    }
    if (tid < NLAYERS * NQ) {
        float phi   = weights[tid * 3 + 0];
        float theta = weights[tid * 3 + 1];
        float omega = weights[tid * 3 + 2];
        float st, ct; sincosf(0.5f * theta, &st, &ct);
        float sp, cp; sincosf(0.5f * (phi + omega), &sp, &cp);
        float sm, cm; sincosf(0.5f * (phi - omega), &sm, &cm);
        smat[tid] = make_float4(cp * ct, -sp * ct, -cm * st, -sm * st);
    }
    __syncthreads();

    // init, identity basis: k = (tid<<4)|(h<<3)|j; local bits 0-2 <-> wires
    // 11,10,9; pack bit 3 <-> wire 8; tid bit j <-> wire 7-j.
    float base = 1.0f;
    #pragma unroll
    for (int j = 0; j < 8; j++) {
        int w = 7 - j;
        base *= ((tid >> j) & 1) ? sss[w] : scs[w];
    }
    v2f PRE[8], PIM[8];
    float c8 = scs[8], s8 = sss[8];
    #pragma unroll
    for (int j = 0; j < 8; j++) {
        float a = base;
        #pragma unroll
        for (int p = 0; p < 3; p++) {
            int w = NQ - 1 - p;
            a *= ((j >> p) & 1) ? sss[w] : scs[w];
        }
        PRE[j].x = a * c8;  PRE[j].y = a * s8;
        PIM[j].x = 0.0f;    PIM[j].y = 0.0f;
    }

    // fixed-pass address bases
    uint32_t pawb = 0, parb = 0, pbwb = 0, pbrb = 0;
    #pragma unroll
    for (int j = 0; j < 6; j++) {
        uint32_t sel = (uint32_t)(-(int)((tid >> j) & 1));
        pawb ^= sel & CK.PA.WT[j]; parb ^= sel & CK.PA.RT[j];
    }
    #pragma unroll
    for (int j = 0; j < 8; j++) {
        uint32_t sel = (uint32_t)(-(int)((tid >> j) & 1));
        pbwb ^= sel & CK.PB.WT[j]; pbrb ^= sel & CK.PB.RT[j];
    }
    {
        uint32_t wvb = (uint32_t)(tid & 0xC0) << 4;   // wave id -> slot bits 10,11
        pawb |= wvb; parb |= wvb;
    }

    float* bufA = lds;
    float* bufB = lds + 2 * DIM;

    #pragma clang loop unroll(disable)
    for (int l = 0; l < NLAYERS; l++) {
        if (l > 0) rebase_pass(PRE, PIM, bufB, tid, l);
        const int sb = l * NQ;
        gate_q<0>(PRE, PIM, smat[sb + 11]);
        gate_q<1>(PRE, PIM, smat[sb + 10]);
        gate_q<2>(PRE, PIM, smat[sb + 9]);
        pack_gate(PRE, PIM, smat[sb + 8]);
        pa_pass(PRE, PIM, bufA, pawb, parb);
        gate_q<0>(PRE, PIM, smat[sb + 7]);
        gate_q<1>(PRE, PIM, smat[sb + 6]);
        gate_q<2>(PRE, PIM, smat[sb + 5]);
        pack_gate(PRE, PIM, smat[sb + 4]);
        pb_pass(PRE, PIM, bufA, pbwb, pbrb);
        gate_q<0>(PRE, PIM, smat[sb + 3]);
        gate_q<1>(PRE, PIM, smat[sb + 2]);
        gate_q<2>(PRE, PIM, smat[sb + 1]);
        pack_gate(PRE, PIM, smat[sb + 0]);
    }

    // expectation: coef = b + sum_p W[11-p]*(1-2*bit_p(i(k))), packed halves
    const float bv = bptr[0];
    float wbT[NQ];
    #pragma unroll
    for (int p = 0; p < NQ; p++) {
        uint32_t row = CK.frow[p];
        int tp = __popc(tid & (int)(row >> 4)) & 1;
        float Wv = Wp[NQ - 1 - p];
        wbT[p] = tp ? -Wv : Wv;
    }
    v2f acc2 = {0.0f, 0.0f};
    #pragma unroll
    for (int j = 0; j < 8; j++) {
        float cx = bv, cy = bv;
        #pragma unroll
        for (int p = 0; p < NQ; p++) {
            uint32_t row = CK.frow[p];
            float s = (__popc(j & (int)(row & 7u)) & 1) ? -wbT[p] : wbT[p];
            cx += s;
            cy += (row & 8u) ? -s : s;
        }
        v2f c = {cx, cy};
        acc2 += (PRE[j] * PRE[j] + PIM[j] * PIM[j]) * c;
    }
    float acc = acc2.x + acc2.y;
    #pragma unroll
    for (int off = 32; off > 0; off >>= 1)
        acc += __shfl_down(acc, off, 64);
    if ((tid & 63) == 0) red[tid >> 6] = acc;
    __syncthreads();
    if (tid == 0) out[b] = red[0] + red[1] + red[2] + red[3];
}

extern "C" void kernel_launch(void* const* d_in, const int* in_sizes, int n_in,
                              void* d_out, int out_size, void* d_ws, size_t ws_size,
                              hipStream_t stream) {
    const float* x       = (const float*)d_in[0];
    const float* weights = (const float*)d_in[1];
    const float* W       = (const float*)d_in[2];
    const float* bptr    = (const float*)d_in[3];
    qsim_kernel<<<512, TPB, 0, stream>>>(x, weights, W, bptr, (float*)d_out);
}

// Round 9
// 90.057 us; speedup vs baseline: 1.0971x; 1.0470x over previous
//
#include <hip/hip_runtime.h>
#include <stdint.h>

#define NQ 12
#define DIM 4096
#define NLAYERS 6
#define TPB 256

typedef float v2f __attribute__((ext_vector_type(2)));

// ---------------------------------------------------------------------------
// R21 = R20 resubmitted (previous round died on container acquisition, no
// data). R12 verbatim (best verified, 39.9us dispatch) + anti-phase stagger.
//   Theory: per-CU LDS-pipe time (~43k cyc) and per-SIMD VALU time (~35k cyc)
//   SUM instead of overlapping because the 2 co-resident blocks run identical
//   barrier-locked schedules in phase: CU alternates {DS busy, VALU idle} <->
//   {VALU busy, DS idle}. A one-time ~960-cycle s_sleep for ONE of the two
//   co-resident blocks establishes anti-phase (A's DS under B's VALU), which
//   is self-stabilizing since both blocks have identical per-pass timing.
//   Class bit chosen so co-resident pairs differ under both plausible
//   mappings: (i, i+256) XCD round-robin -> bit8; (2i, 2i+1) packed -> bit0;
//   class = (bid ^ (bid>>8)) & 1 covers both.
//   Everything else is R12 verbatim:
//   k bits: 0-2 local (gated), 3 pack (v2f lane, gated via pack_gate),
//           4-9 lane (tid 0-5), 10-11 wave (tid 6-7).
//   Layer l: [P_c = rebase: fold CNOT A_{l-1}, cross-wave, 1 barrier]
//            gates w11,w10,w9 + pack w8
//            P_a: swap {0-3}<->{4-7}   (wave-local, lgkmcnt only)
//            gates w7,w6,w5 + pack w4
//            P_b: swap {0-3}<->{8-11}  (cross-wave, pre+post barrier)
//            gates w3,w2,w1 + pack w0
// ---------------------------------------------------------------------------
struct Pass_t {
    uint32_t WT[8];    // Lambda cols, k bits 4..11
    uint32_t WL[8];    // Lambda(j), local bits 0..2
    uint32_t RT[8];    // (Lambda o M) cols, k bits 4..11
    uint32_t RL[16];   // (Lambda o M)(l), local bits 0..3
};
struct Pass10_t {      // wave-local: 10-bit space (k bits 0..9)
    uint32_t WT[6];
    uint32_t WL[8];
    uint32_t RT[6];
    uint32_t RL[16];
};
struct CK_t {
    Pass10_t PA;           // swap {0-3}<->{4-7}, wave-local
    Pass_t PB;             // swap {0-3}<->{8-11}, cross-wave
    Pass_t P1[NLAYERS];    // rebase (index 1..5 used)
    uint32_t frow[NQ];     // epilogue sign rows
};

constexpr uint32_t G2f(uint32_t k){ return ((k&15u)<<8) | (k&0xF0u) | ((k>>8)&15u); }
constexpr uint32_t G3f(uint32_t k){ return ((k&15u)<<4) | ((k>>4)&15u) | (k&0xF00u); }

constexpr uint32_t ech_reduce(const uint32_t* v, int n, uint32_t x){
    bool ch = true;
    while (ch) {
        ch = false;
        for (int i = 0; i < n; i++)
            if (v[i] && (x ^ v[i]) < x) { x ^= v[i]; ch = true; }
    }
    return x;
}

constexpr Pass_t build_pass(const uint32_t* Mc) {
    Pass_t P{};
    uint32_t rows[12]{};
    rows[0] = 8u;                              // row0 = pack functional
    int nr = 1;
    uint32_t full[12]{}; int nf = 0; full[nf++] = 8u;
    uint32_t We[4]{};  int nw = 0;
    uint32_t Re[5]{};  int nre = 0;
    {   // row0's read projection over span Mc[4..8]
        uint32_t p0 = 0;
        for (int j = 0; j < 5; j++)
            p0 |= (uint32_t)(__builtin_popcount(8u & Mc[4 + j]) & 1) << j;
        uint32_t r = ech_reduce(Re, nre, p0);
        if (r) Re[nre++] = r;
    }
    for (int slot = 0; slot < 4; slot++) {
        uint32_t chosen = 0;
        for (int relax = 0; relax < 3 && !chosen; relax++) {
            for (uint32_t m = 1; m < 4096u && !chosen; m++) {
                if (m & 8u) continue;
                uint32_t wp = (m >> 4) & 15u;
                uint32_t wr = ech_reduce(We, nw, wp);
                if (relax < 2 && !wr) continue;
                uint32_t rp = 0;
                for (int j = 0; j < 5; j++)
                    rp |= (uint32_t)(__builtin_popcount(m & Mc[4 + j]) & 1) << j;
                uint32_t rr = ech_reduce(Re, nre, rp);
                if (relax < 1 && !rr) continue;
                uint32_t fr = ech_reduce(full, nf, m);
                if (!fr) continue;
                chosen = m; full[nf++] = fr;
                if (wr && nw < 4) We[nw++] = wr;
                if (rr && nre < 5) Re[nre++] = rr;
            }
        }
        rows[nr++] = chosen;
    }
    for (int slot = nr; slot < 12; slot++) {
        for (uint32_t m = 1; m < 4096u; m++) {
            if (m & 8u) continue;
            uint32_t fr = ech_reduce(full, nf, m);
            if (fr) { rows[slot] = m; full[nf++] = fr; break; }
        }
    }
    uint32_t col[12]{}, lmc[12]{};
    for (int j = 0; j < 12; j++) {
        uint32_t c = 0;
        for (int i = 0; i < 12; i++) c |= (uint32_t)((rows[i] >> j) & 1u) << i;
        col[j] = c;
    }
    for (int j = 0; j < 12; j++) {
        uint32_t a = 0, mc = Mc[j];
        for (int q = 0; q < 12; q++) if ((mc >> q) & 1u) a ^= col[q];
        lmc[j] = a;
    }
    for (int j = 0; j < 8; j++) { P.WT[j] = col[4 + j]; P.RT[j] = lmc[4 + j]; }
    for (int j = 0; j < 8; j++) {
        uint32_t a = 0;
        for (int q = 0; q < 3; q++) if ((j >> q) & 1) a ^= col[q];
        P.WL[j] = a;
    }
    for (int l = 0; l < 16; l++) {
        uint32_t a = 0;
        for (int q = 0; q < 4; q++) if ((l >> q) & 1) a ^= lmc[q];
        P.RL[l] = a;
    }
    return P;
}

constexpr Pass10_t build_pass10(const uint32_t* Mc) {
    Pass10_t P{};
    uint32_t rows[10]{};
    rows[0] = 8u;
    int nr = 1;
    uint32_t full[10]{}; int nf = 0; full[nf++] = 8u;
    uint32_t We[4]{};  int nw = 0;
    uint32_t Re[5]{};  int nre = 0;
    {
        uint32_t p0 = 0;
        for (int j = 0; j < 5; j++)
            p0 |= (uint32_t)(__builtin_popcount(8u & Mc[4 + j]) & 1) << j;
        uint32_t r = ech_reduce(Re, nre, p0);
        if (r) Re[nre++] = r;
    }
    for (int slot = 0; slot < 4; slot++) {
        uint32_t chosen = 0;
        for (int relax = 0; relax < 3 && !chosen; relax++) {
            for (uint32_t m = 1; m < 1024u && !chosen; m++) {
                if (m & 8u) continue;
                uint32_t wp = (m >> 4) & 15u;
                uint32_t wr = ech_reduce(We, nw, wp);
                if (relax < 2 && !wr) continue;
                uint32_t rp = 0;
                for (int j = 0; j < 5; j++)
                    rp |= (uint32_t)(__builtin_popcount(m & Mc[4 + j]) & 1) << j;
                uint32_t rr = ech_reduce(Re, nre, rp);
                if (relax < 1 && !rr) continue;
                uint32_t fr = ech_reduce(full, nf, m);
                if (!fr) continue;
                chosen = m; full[nf++] = fr;
                if (wr && nw < 4) We[nw++] = wr;
                if (rr && nre < 5) Re[nre++] = rr;
            }
        }
        rows[nr++] = chosen;
    }
    for (int slot = nr; slot < 10; slot++) {
        for (uint32_t m = 1; m < 1024u; m++) {
            if (m & 8u) continue;
            uint32_t fr = ech_reduce(full, nf, m);
            if (fr) { rows[slot] = m; full[nf++] = fr; break; }
        }
    }
    uint32_t col[10]{}, lmc[10]{};
    for (int j = 0; j < 10; j++) {
        uint32_t c = 0;
        for (int i = 0; i < 10; i++) c |= (uint32_t)((rows[i] >> j) & 1u) << i;
        col[j] = c;
    }
    for (int j = 0; j < 10; j++) {
        uint32_t a = 0, mc = Mc[j];
        for (int q = 0; q < 10; q++) if ((mc >> q) & 1u) a ^= col[q];
        lmc[j] = a;
    }
    for (int j = 0; j < 6; j++) { P.WT[j] = col[4 + j]; P.RT[j] = lmc[4 + j]; }
    for (int j = 0; j < 8; j++) {
        uint32_t a = 0;
        for (int q = 0; q < 3; q++) if ((j >> q) & 1) a ^= col[q];
        P.WL[j] = a;
    }
    for (int l = 0; l < 16; l++) {
        uint32_t a = 0;
        for (int q = 0; q < 4; q++) if ((l >> q) & 1) a ^= lmc[q];
        P.RL[l] = a;
    }
    return P;
}

constexpr CK_t build_ck() {
    CK_t ck{};
    uint32_t Acols[NLAYERS][NQ]{}, Aicol5[NQ]{};
    for (int l = 0; l < NLAYERS; l++) {
        int r = l % (NQ - 1) + 1;
        for (int q = 0; q < NQ; q++) {
            uint32_t v = 1u << q;
            for (int w = NQ - 1; w >= 0; w--) {            // A = T0∘T1∘...∘T11
                int pc = NQ - 1 - w, pt = NQ - 1 - ((w + r) % NQ);
                v ^= ((v >> pc) & 1u) << pt;
            }
            Acols[l][q] = v;
            if (l == NLAYERS - 1) {
                uint32_t u = 1u << q;
                for (int w = 0; w < NQ; w++) {             // A^-1
                    int pc = NQ - 1 - w, pt = NQ - 1 - ((w + r) % NQ);
                    u ^= ((u >> pc) & 1u) << pt;
                }
                Aicol5[q] = u;
            }
        }
    }
    uint32_t Mc10[10]{};
    for (int j = 0; j < 10; j++) Mc10[j] = G3f(1u << j);      // M_a
    ck.PA = build_pass10(Mc10);
    uint32_t Mc[12]{};
    for (int j = 0; j < 12; j++) Mc[j] = G2f(1u << j);        // M_b
    ck.PB = build_pass(Mc);
    for (int l = 1; l < NLAYERS; l++) {                       // M_c = M_b.M_a.A
        for (int j = 0; j < 12; j++) Mc[j] = G2f(G3f(Acols[l - 1][j]));
        ck.P1[l] = build_pass(Mc);
    }
    // epilogue: i(k) = A5^-1(Phi(k)), Phi = M_a.M_b  (col: G3f(G2f(e_j)))
    uint32_t Mcol[NQ]{};
    for (int j = 0; j < NQ; j++) {
        uint32_t pj = G3f(G2f(1u << j));
        uint32_t M = 0;
        for (int m = 0; m < NQ; m++) if ((pj >> m) & 1u) M ^= Aicol5[m];
        Mcol[j] = M;
    }
    for (int p = 0; p < NQ; p++) {
        uint32_t s = 0;
        for (int j = 0; j < NQ; j++) s |= ((Mcol[j] >> p) & 1u) << j;
        ck.frow[p] = s;
    }
    return ck;
}
constexpr CK_t CK = build_ck();

// rotation at local bit Q; m = (m00r,m00i,m01r,m01i); element-wise pk math.
template<int Q>
__device__ __forceinline__ void gate_q(v2f (&PRE)[8], v2f (&PIM)[8], float4 m) {
    v2f bx = {m.x, m.x}, by = {m.y, m.y}, bz = {m.z, m.z}, bw = {m.w, m.w};
    #pragma unroll
    for (int j = 0; j < 8; j++) {
        if (j & (1 << Q)) continue;
        int j2 = j | (1 << Q);
        v2f re0 = PRE[j], im0 = PIM[j], re1 = PRE[j2], im1 = PIM[j2];
        PRE[j]  = __builtin_elementwise_fma(bx, re0,
                  __builtin_elementwise_fma(by, -im0,
                  __builtin_elementwise_fma(bz, re1, -bw * im1)));
        PIM[j]  = __builtin_elementwise_fma(bx, im0,
                  __builtin_elementwise_fma(by, re0,
                  __builtin_elementwise_fma(bz, im1, bw * re1)));
        PRE[j2] = __builtin_elementwise_fma(bx, re1,
                  __builtin_elementwise_fma(by, im1,
                  __builtin_elementwise_fma(bz, -re0, -bw * im0)));
        PIM[j2] = __builtin_elementwise_fma(bx, im1,
                  __builtin_elementwise_fma(by, -re1,
                  __builtin_elementwise_fma(bz, -im0, bw * re0)));
    }
}

// gate on the pack bit (halves .x/.y of each v2f), sign-vector pk math.
__device__ __forceinline__ void pack_gate(v2f (&PRE)[8], v2f (&PIM)[8], float4 m) {
    v2f d1 = {-m.y, m.y}, d2 = {m.z, -m.z};
    #pragma unroll
    for (int j = 0; j < 8; j++) {
        v2f RE = PRE[j], IM = PIM[j];
        v2f sR = {RE.y, RE.x}, sI = {IM.y, IM.x};
        PRE[j] = m.x * RE + d1 * IM + d2 * sR - m.w * sI;
        PIM[j] = m.x * IM - d1 * RE + d2 * sI + m.w * sR;
    }
}

// wave-local P_a: b64 writes, lgkmcnt drain, b32 scatter reads (R12 verbatim)
__device__ __forceinline__ void pa_pass(v2f (&PRE)[8], v2f (&PIM)[8],
                                        float* buf, uint32_t wb, uint32_t rb) {
    constexpr Pass10_t P = CK.PA;
    v2f* bre = (v2f*)buf;
    v2f* bim = (v2f*)(buf + DIM);
    #pragma unroll
    for (int j = 0; j < 8; j++) {
        uint32_t s = (wb ^ P.WL[j]) >> 1;
        bre[s] = PRE[j]; bim[s] = PIM[j];
    }
    __asm__ volatile("s_waitcnt lgkmcnt(0)" ::: "memory");
    #pragma unroll
    for (int j = 0; j < 8; j++) {
        uint32_t s0 = rb ^ P.RL[j], s1 = rb ^ P.RL[j | 8];
        v2f re, im;
        re.x = buf[s0];       re.y = buf[s1];
        im.x = buf[DIM + s0]; im.y = buf[DIM + s1];
        PRE[j] = re; PIM[j] = im;
    }
}

// cross-wave P_b: pre-barrier (drain P_a reads block-wide), write, barrier, read
__device__ __forceinline__ void pb_pass(v2f (&PRE)[8], v2f (&PIM)[8],
                                        float* buf, uint32_t wb, uint32_t rb) {
    constexpr Pass_t P = CK.PB;
    v2f* bre = (v2f*)buf;
    v2f* bim = (v2f*)(buf + DIM);
    __syncthreads();
    #pragma unroll
    for (int j = 0; j < 8; j++) {
        uint32_t s = (wb ^ P.WL[j]) >> 1;
        bre[s] = PRE[j]; bim[s] = PIM[j];
    }
    __syncthreads();
    #pragma unroll
    for (int j = 0; j < 8; j++) {
        uint32_t s0 = rb ^ P.RL[j], s1 = rb ^ P.RL[j | 8];
        v2f re, im;
        re.x = buf[s0];       re.y = buf[s1];
        im.x = buf[DIM + s0]; im.y = buf[DIM + s1];
        PRE[j] = re; PIM[j] = im;
    }
}

// cross-wave rebase P_c, runtime layer index (R12 verbatim)
__device__ __forceinline__ void rebase_pass(v2f (&PRE)[8], v2f (&PIM)[8],
                                            float* buf, int tid, int l) {
    const Pass_t& P = CK.P1[l];
    uint32_t wb = 0, rb = 0;
    #pragma unroll
    for (int j = 0; j < 8; j++) {
        uint32_t sel = (uint32_t)(-(int)((tid >> j) & 1));
        wb ^= sel & P.WT[j];
        rb ^= sel & P.RT[j];
    }
    v2f* bre = (v2f*)buf;
    v2f* bim = (v2f*)(buf + DIM);
    #pragma unroll
    for (int j = 0; j < 8; j++) {
        uint32_t s = (wb ^ P.WL[j]) >> 1;
        bre[s] = PRE[j]; bim[s] = PIM[j];
    }
    __syncthreads();
    #pragma unroll
    for (int j = 0; j < 8; j++) {
        uint32_t s0 = rb ^ P.RL[j], s1 = rb ^ P.RL[j | 8];
        v2f re, im;
        re.x = buf[s0];       re.y = buf[s1];
        im.x = buf[DIM + s0]; im.y = buf[DIM + s1];
        PRE[j] = re; PIM[j] = im;
    }
}

__global__ __launch_bounds__(TPB) void qsim_kernel(
    const float* __restrict__ x,        // [512,12]
    const float* __restrict__ weights,  // [6,12,3]
    const float* __restrict__ Wp,       // [12]
    const float* __restrict__ bptr,     // [1]
    float* __restrict__ out)            // [512]
{
    __shared__ float  lds[2 * 2 * DIM]; // bufA [0,8192): P_a/P_b; bufB: rebase
    __shared__ float4 smat[NLAYERS * NQ];
    __shared__ float  scs[NQ], sss[NQ];
    __shared__ float  red[4];

    const int tid = threadIdx.x;
    const int b   = blockIdx.x;

    // R20/R21: anti-phase stagger — one of each co-resident block pair sleeps
    // ~960 cycles once, so its DS phases land under the other's VALU phases.
    if ((b ^ (b >> 8)) & 1)
        __builtin_amdgcn_s_sleep(15);

    if (tid < NQ) {
        float s_, c_;
        sincosf(0.5f * x[b * NQ + tid], &s_, &c_);
        scs[tid] = c_; sss[tid] = s_;
    }
    if (tid < NLAYERS * NQ) {
        float phi   = weights[tid * 3 + 0];
        float theta = weights[tid * 3 + 1];
        float omega = weights[tid * 3 + 2];
        float st, ct; sincosf(0.5f * theta, &st, &ct);
        float sp, cp; sincosf(0.5f * (phi + omega), &sp, &cp);
        float sm, cm; sincosf(0.5f * (phi - omega), &sm, &cm);
        smat[tid] = make_float4(cp * ct, -sp * ct, -cm * st, -sm * st);
    }
    __syncthreads();

    // init, identity basis: k = (tid<<4)|(h<<3)|j; local bits 0-2 <-> wires
    // 11,10,9; pack bit 3 <-> wire 8; tid bit j <-> wire 7-j.
    float base = 1.0f;
    #pragma unroll
    for (int j = 0; j < 8; j++) {
        int w = 7 - j;
        base *= ((tid >> j) & 1) ? sss[w] : scs[w];
    }
    v2f PRE[8], PIM[8];
    float c8 = scs[8], s8 = sss[8];
    #pragma unroll
    for (int j = 0; j < 8; j++) {
        float a = base;
        #pragma unroll
        for (int p = 0; p < 3; p++) {
            int w = NQ - 1 - p;
            a *= ((j >> p) & 1) ? sss[w] : scs[w];
        }
        PRE[j].x = a * c8;  PRE[j].y = a * s8;
        PIM[j].x = 0.0f;    PIM[j].y = 0.0f;
    }

    // fixed-pass address bases
    uint32_t pawb = 0, parb = 0, pbwb = 0, pbrb = 0;
    #pragma unroll
    for (int j = 0; j < 6; j++) {
        uint32_t sel = (uint32_t)(-(int)((tid >> j) & 1));
        pawb ^= sel & CK.PA.WT[j]; parb ^= sel & CK.PA.RT[j];
    }
    #pragma unroll
    for (int j = 0; j < 8; j++) {
        uint32_t sel = (uint32_t)(-(int)((tid >> j) & 1));
        pbwb ^= sel & CK.PB.WT[j]; pbrb ^= sel & CK.PB.RT[j];
    }
    {
        uint32_t wvb = (uint32_t)(tid & 0xC0) << 4;   // wave id -> slot bits 10,11
        pawb |= wvb; parb |= wvb;
    }

    float* bufA = lds;
    float* bufB = lds + 2 * DIM;

    #pragma clang loop unroll(disable)
    for (int l = 0; l < NLAYERS; l++) {
        if (l > 0) rebase_pass(PRE, PIM, bufB, tid, l);
        const int sb = l * NQ;
        gate_q<0>(PRE, PIM, smat[sb + 11]);
        gate_q<1>(PRE, PIM, smat[sb + 10]);
        gate_q<2>(PRE, PIM, smat[sb + 9]);
        pack_gate(PRE, PIM, smat[sb + 8]);
        pa_pass(PRE, PIM, bufA, pawb, parb);
        gate_q<0>(PRE, PIM, smat[sb + 7]);
        gate_q<1>(PRE, PIM, smat[sb + 6]);
        gate_q<2>(PRE, PIM, smat[sb + 5]);
        pack_gate(PRE, PIM, smat[sb + 4]);
        pb_pass(PRE, PIM, bufA, pbwb, pbrb);
        gate_q<0>(PRE, PIM, smat[sb + 3]);
        gate_q<1>(PRE, PIM, smat[sb + 2]);
        gate_q<2>(PRE, PIM, smat[sb + 1]);
        pack_gate(PRE, PIM, smat[sb + 0]);
    }

    // expectation: coef = b + sum_p W[11-p]*(1-2*bit_p(i(k))), packed halves
    const float bv = bptr[0];
    float wbT[NQ];
    #pragma unroll
    for (int p = 0; p < NQ; p++) {
        uint32_t row = CK.frow[p];
        int tp = __popc(tid & (int)(row >> 4)) & 1;
        float Wv = Wp[NQ - 1 - p];
        wbT[p] = tp ? -Wv : Wv;
    }
    v2f acc2 = {0.0f, 0.0f};
    #pragma unroll
    for (int j = 0; j < 8; j++) {
        float cx = bv, cy = bv;
        #pragma unroll
        for (int p = 0; p < NQ; p++) {
            uint32_t row = CK.frow[p];
            float s = (__popc(j & (int)(row & 7u)) & 1) ? -wbT[p] : wbT[p];
            cx += s;
            cy += (row & 8u) ? -s : s;
        }
        v2f c = {cx, cy};
        acc2 += (PRE[j] * PRE[j] + PIM[j] * PIM[j]) * c;
    }
    float acc = acc2.x + acc2.y;
    #pragma unroll
    for (int off = 32; off > 0; off >>= 1)
        acc += __shfl_down(acc, off, 64);
    if ((tid & 63) == 0) red[tid >> 6] = acc;
    __syncthreads();
    if (tid == 0) out[b] = red[0] + red[1] + red[2] + red[3];
}

extern "C" void kernel_launch(void* const* d_in, const int* in_sizes, int n_in,
                              void* d_out, int out_size, void* d_ws, size_t ws_size,
                              hipStream_t stream) {
    const float* x       = (const float*)d_in[0];
    const float* weights = (const float*)d_in[1];
    const float* W       = (const float*)d_in[2];
    const float* bptr    = (const float*)d_in[3];
    qsim_kernel<<<512, TPB, 0, stream>>>(x, weights, W, bptr, (float*)d_out);
}